// Round 12
// baseline (1466.053 us; speedup 1.0000x reference)
//
#include <hip/hip_runtime.h>

// ---------------------------------------------------------------------------
// EdgeGatedConv — round 12: r11 pipeline + 16B/lane segment kernels.
//   r11 post-mortem: tied with r8 (1449->1447); plateau. Last lever: the two
//   big streaming kernels read bf16 rows at 8B/lane (32 lanes/row). Now 16
//   lanes/row @ 16B/lane (G13 sweet spot): 4 edges|nodes per wave, LN reduce
//   4 xor steps. Per-column sums bitwise identical (same j-order).
//   K1 k_line_csr:      GEMM (CSR order via perm_lg) -> msg[p] sequential
//   K2 k_lg_edge_fused: out_lg = bf(lg_x)+mean(msg); out_edge =
//                       LN(edge_attr+out_lg); enew_bf = bf16(out_edge)
//   K3 k_gate_csr<BF>:  gate GEMM (A-frags->LDS); gated row at pos_at[e]
//   K4 k_atom_gather:   agg_bf[n] = sum(gated[o0:o1])  (contiguous, bf16)
//   K5 k_atom_mfma:     h=silu([x,agg]@Wa+b); out_x = LN(x+h)
// MFMA 16x16x32 bf16: A row=lane&15, B col=lane&15, k=(lane>>4)*8+j both ops;
// C/D col=lane&15, row=(lane>>4)*4+reg.
// ---------------------------------------------------------------------------

typedef __attribute__((ext_vector_type(8))) short s16x8;
typedef __attribute__((ext_vector_type(4))) float f32x4;

#define SCAN_CHUNK 2048

__device__ __forceinline__ short f2bf(float f) {
    unsigned u = __float_as_uint(f);
    u += 0x7FFF + ((u >> 16) & 1);
    return (short)(u >> 16);
}
__device__ __forceinline__ float bf2f(unsigned short h) {
    return __uint_as_float(((unsigned)h) << 16);
}
__device__ __forceinline__ s16x8 pack8(const float* v) {
    s16x8 r;
    #pragma unroll
    for (int j = 0; j < 8; ++j) r[j] = f2bf(v[j]);
    return r;
}

// ---------------- merged prep: pack3 + cvt + hist2 ----------------
__global__ __launch_bounds__(256) void k_prep(
    const float* __restrict__ Wl, const float* __restrict__ Wg,
    const float* __restrict__ Wa,
    short* __restrict__ Pl, short* __restrict__ Pg, short* __restrict__ Pa,
    const float* __restrict__ lgx, short* __restrict__ lgx_bf, long n8,
    const int* __restrict__ idx1, int* __restrict__ deg1, int n1,
    const int* __restrict__ idx2, int* __restrict__ deg2, int n2,
    int cvtBlocks)
{
    const int b = blockIdx.x;
    if (b < 40) {                              // weight pack
        int c = b * 256 + threadIdx.x;
        const float* W; short* P; int cc;
        if (c < 4096)       { W = Wl; P = Pl; cc = c; }
        else if (c < 6144)  { W = Wg; P = Pg; cc = c - 4096; }
        else if (c < 10240) { W = Wa; P = Pa; cc = c - 6144; }
        else return;
        int g = cc >> 7, col = cc & 127, k0 = g * 8;
        s16x8 v;
        #pragma unroll
        for (int j = 0; j < 8; ++j) v[j] = f2bf(W[(size_t)(k0 + j) * 128 + col]);
        ((s16x8*)P)[cc] = v;
    } else if (b < 40 + cvtBlocks) {           // lg_x -> bf16
        long i = (long)(b - 40) * 256 + threadIdx.x;
        const long stride = (long)cvtBlocks * 256;
        for (; i < n8; i += stride) {
            float buf[8];
            *(float4*)&buf[0] = ((const float4*)lgx)[2 * i];
            *(float4*)&buf[4] = ((const float4*)lgx)[2 * i + 1];
            ((s16x8*)lgx_bf)[i] = pack8(buf);
        }
    } else {                                   // dual histogram
        int i = (b - 40 - cvtBlocks) * 256 + threadIdx.x;
        if (i < n1) atomicAdd(&deg1[idx1[i]], 1);
        if (i < n2) atomicAdd(&deg2[idx2[i]], 1);
    }
}

// ---------------- CSR build ----------------
__global__ __launch_bounds__(256) void k_scan_block2(
    const int* __restrict__ in1, int n1, int* __restrict__ out1, int* __restrict__ bsum1, int nb1,
    const int* __restrict__ in2, int n2, int* __restrict__ out2, int* __restrict__ bsum2)
{
    __shared__ int ts[256];
    int b = blockIdx.x;
    const int* in; int n; int* out; int* bsum;
    if (b < nb1) { in = in1; n = n1; out = out1; bsum = bsum1; }
    else         { in = in2; n = n2; out = out2; bsum = bsum2; b -= nb1; }
    const int t = threadIdx.x;
    const int base = b * SCAN_CHUNK + t * 8;
    int v[8]; int s = 0;
    #pragma unroll
    for (int i = 0; i < 8; ++i) { v[i] = (base + i < n) ? in[base + i] : 0; s += v[i]; }
    ts[t] = s;
    __syncthreads();
    int x = s;
    for (int off = 1; off < 256; off <<= 1) {
        int y = (t >= off) ? ts[t - off] : 0;
        __syncthreads();
        x += y; ts[t] = x;
        __syncthreads();
    }
    if (t == 255) bsum[b] = x;
    int run = x - s;
    #pragma unroll
    for (int i = 0; i < 8; ++i) {
        if (base + i < n) out[base + i] = run;
        run += v[i];
    }
}

__global__ void k_scan_bsum2(int* __restrict__ b1, int nb1,
                             int* __restrict__ b2, int nb2) {  // 128 thr = 2 waves
    const int lane = threadIdx.x & 63;
    int* bsum = (threadIdx.x < 64) ? b1 : b2;
    const int nb  = (threadIdx.x < 64) ? nb1 : nb2;
    int carry = 0;
    for (int base = 0; base < nb; base += 64) {
        int i = base + lane;
        int v = (i < nb) ? bsum[i] : 0;
        int inc = v;
        #pragma unroll
        for (int off = 1; off < 64; off <<= 1) {
            int t = __shfl_up(inc, off);
            if (lane >= off) inc += t;
        }
        if (i < nb) bsum[i] = inc - v + carry;
        carry += __shfl(inc, 63);
    }
}

__global__ __launch_bounds__(256) void k_scan_add2(
    int* __restrict__ off1, const int* __restrict__ bsum1, int n1, int ne1,
    int* __restrict__ off2, const int* __restrict__ bsum2, int n2, int ne2)
{
    int i = blockIdx.x * 256 + threadIdx.x;
    if (i < n1) off1[i] += bsum1[i / SCAN_CHUNK];
    if (i < n2) off2[i] += bsum2[i / SCAN_CHUNK];
    if (i == 0) { off1[n1] = ne1; off2[n2] = ne2; }
}

// graph1: perm (pos -> edge); graph2: pos (edge -> pos)
__global__ __launch_bounds__(256) void k_fill2(
    const int* __restrict__ idx1, const int* __restrict__ off1,
    int* __restrict__ cur1, int* __restrict__ perm1, int n1,
    const int* __restrict__ idx2, const int* __restrict__ off2,
    int* __restrict__ cur2, int* __restrict__ pos2, int n2)
{
    int i = blockIdx.x * 256 + threadIdx.x;
    if (i < n1) {
        int s = idx1[i];
        int p = atomicAdd(&cur1[s], 1);
        perm1[off1[s] + p] = i;
    }
    if (i < n2) {
        int s = idx2[i];
        int p = atomicAdd(&cur2[s], 1);
        pos2[i] = off2[s] + p;
    }
}

// ---------------- K1: line GEMM in CSR order -> msg[p] sequential ----------------
__global__ __launch_bounds__(256) void k_line_csr(
    const short* __restrict__ lgx_bf, const float* __restrict__ lg_ea,
    const short* __restrict__ Wp, const float* __restrict__ W_line,
    const float* __restrict__ b_line,
    const int* __restrict__ lg_src, const int* __restrict__ lg_dst,
    const int* __restrict__ perm_lg,
    short* __restrict__ msg, int LEn)
{
    __shared__ __align__(16) short sh[128][136];
    const int tid = threadIdx.x;
    const int ln = tid & 63, wv = tid >> 6;
    const int l15 = ln & 15, lhi = ln >> 4;
    const int pb = blockIdx.x * 128 + wv * 32;
    const s16x8* Bv = (const s16x8*)Wp;

    const short *sp[2], *dp[2];
    #pragma unroll
    for (int mt = 0; mt < 2; ++mt) {
        int p = pb + mt * 16 + l15;
        int pc = p < LEn ? p : LEn - 1;
        int e = perm_lg[pc];
        sp[mt] = lgx_bf + (size_t)lg_src[e] * 128;
        dp[mt] = lgx_bf + (size_t)lg_dst[e] * 128;   // monotone in CSR order
    }

    f32x4 acc[2][8];
    #pragma unroll
    for (int m = 0; m < 2; ++m)
        #pragma unroll
        for (int n = 0; n < 8; ++n) acc[m][n] = (f32x4){0.f, 0.f, 0.f, 0.f};

    #pragma unroll 2
    for (int kt = 0; kt < 8; ++kt) {
        int ko = (kt & 3) * 32 + lhi * 8;
        s16x8 a[2];
        #pragma unroll
        for (int mt = 0; mt < 2; ++mt)
            a[mt] = *(const s16x8*)(((kt < 4) ? sp[mt] : dp[mt]) + ko);
        const s16x8* brow = Bv + (size_t)(kt * 4 + lhi) * 128 + l15;
        #pragma unroll
        for (int nt = 0; nt < 8; ++nt) {
            s16x8 b = brow[nt * 16];
            acc[0][nt] = __builtin_amdgcn_mfma_f32_16x16x32_bf16(a[0], b, acc[0][nt], 0, 0, 0);
            acc[1][nt] = __builtin_amdgcn_mfma_f32_16x16x32_bf16(a[1], b, acc[1][nt], 0, 0, 0);
        }
    }

    float eav[2][4];
    #pragma unroll
    for (int mt = 0; mt < 2; ++mt)
        #pragma unroll
        for (int r = 0; r < 4; ++r) {
            int p = pb + mt * 16 + lhi * 4 + r;
            int pc = p < LEn ? p : LEn - 1;
            eav[mt][r] = lg_ea[perm_lg[pc]];
        }

    #pragma unroll
    for (int nt = 0; nt < 8; ++nt) {
        int col = nt * 16 + l15;
        float wl = W_line[(size_t)256 * 128 + col];
        float bs = b_line[col];
        #pragma unroll
        for (int mt = 0; mt < 2; ++mt)
            #pragma unroll
            for (int r = 0; r < 4; ++r) {
                float v = acc[mt][nt][r] + bs + wl * eav[mt][r];
                float s = v / (1.f + __expf(-v));
                sh[wv * 32 + mt * 16 + lhi * 4 + r][col] = f2bf(s);
            }
    }
    __syncthreads();
    #pragma unroll
    for (int i = 0; i < 8; ++i) {
        int c = tid + i * 256;
        int row = c >> 4, q = c & 15;
        int p = blockIdx.x * 128 + row;
        if (p < LEn)
            *(s16x8*)&msg[(size_t)p * 128 + q * 8] = *(const s16x8*)&sh[row][q * 8];
    }
}

// ---------------- K2: fused gather-mean + residual + edge LN (4 edges/wave, 16B/lane) ----------------
__global__ __launch_bounds__(256) void k_lg_edge_fused(
    const short* __restrict__ msg, const short* __restrict__ lgx_bf,
    const float* __restrict__ edge_attr, const int* __restrict__ off,
    const float* __restrict__ g_edge, const float* __restrict__ beta_edge,
    float* __restrict__ out_lg, float* __restrict__ out_edge,
    short* __restrict__ enew_bf, int En)
{
    const int wave = threadIdx.x >> 6, lane = threadIdx.x & 63;
    const int sub = lane >> 4, l = lane & 15;       // 4 edges/wave, 16 lanes each
    const int e = blockIdx.x * 16 + wave * 4 + sub;
    if (e >= En) return;
    const int o0 = off[e], o1 = off[e + 1];
    const int cnt = o1 - o0;
    const short* mbase = msg + (size_t)o0 * 128 + l * 8;
    float s[8];
    #pragma unroll
    for (int k = 0; k < 8; ++k) s[k] = 0.f;
    for (int j = 0; j < cnt; ++j) {
        s16x8 u = *(const s16x8*)(mbase + (size_t)j * 128);
        #pragma unroll
        for (int k = 0; k < 8; ++k) s[k] += bf2f((unsigned short)u[k]);
    }
    const float inv = 1.f / fmaxf((float)cnt, 1.f);
    const size_t rb = (size_t)e * 128 + l * 8;
    s16x8 lxu = *(const s16x8*)&lgx_bf[rb];
    float lv[8];
    #pragma unroll
    for (int k = 0; k < 8; ++k) lv[k] = fmaf(s[k], inv, bf2f((unsigned short)lxu[k]));
    *(float4*)&out_lg[rb]     = make_float4(lv[0], lv[1], lv[2], lv[3]);
    *(float4*)&out_lg[rb + 4] = make_float4(lv[4], lv[5], lv[6], lv[7]);

    float ea[8];
    *(float4*)&ea[0] = *(const float4*)&edge_attr[rb];
    *(float4*)&ea[4] = *(const float4*)&edge_attr[rb + 4];
    float t[8], ssum = 0.f, sq = 0.f;
    #pragma unroll
    for (int k = 0; k < 8; ++k) {
        t[k] = ea[k] + lv[k];
        ssum += t[k]; sq += t[k] * t[k];
    }
    #pragma unroll
    for (int o = 8; o; o >>= 1) {               // reduce within 16-lane group
        ssum += __shfl_xor(ssum, o);
        sq   += __shfl_xor(sq, o);
    }
    float mean = ssum * (1.f / 128.f);
    float var  = sq * (1.f / 128.f) - mean * mean;
    float r = rsqrtf(var + 1e-5f);
    float gg[8], bb[8];
    *(float4*)&gg[0] = *(const float4*)&g_edge[l * 8];
    *(float4*)&gg[4] = *(const float4*)&g_edge[l * 8 + 4];
    *(float4*)&bb[0] = *(const float4*)&beta_edge[l * 8];
    *(float4*)&bb[4] = *(const float4*)&beta_edge[l * 8 + 4];
    float eo[8];
    s16x8 ub;
    #pragma unroll
    for (int k = 0; k < 8; ++k) {
        eo[k] = fmaf((t[k] - mean) * r, gg[k], bb[k]);
        ub[k] = f2bf(eo[k]);
    }
    *(float4*)&out_edge[rb]     = make_float4(eo[0], eo[1], eo[2], eo[3]);
    *(float4*)&out_edge[rb + 4] = make_float4(eo[4], eo[5], eo[6], eo[7]);
    if (enew_bf) *(s16x8*)&enew_bf[rb] = ub;
}

// ---------------- tier-B: unfused gather + LN ----------------
__global__ __launch_bounds__(256) void k_lg_gather(
    const short* __restrict__ msg, const float* __restrict__ lg_x,
    const int* __restrict__ off, float* __restrict__ out_lg, int En)
{
    const int wave = threadIdx.x >> 6, lane = threadIdx.x & 63;
    const int e = blockIdx.x * 4 + wave;
    if (e >= En) return;
    const int o0 = off[e], o1 = off[e + 1];
    const int cnt = o1 - o0;
    const short* base = msg + (size_t)o0 * 128 + lane * 2;
    float s0 = 0.f, s1 = 0.f;
    for (int j = 0; j < cnt; ++j) {
        ushort2 u = *(const ushort2*)(base + (size_t)j * 128);
        s0 += bf2f(u.x); s1 += bf2f(u.y);
    }
    const float inv = 1.f / fmaxf((float)cnt, 1.f);
    const size_t rb = (size_t)e * 128 + lane * 2;
    float2 lx = *(const float2*)&lg_x[rb];
    *(float2*)&out_lg[rb] = make_float2(fmaf(s0, inv, lx.x), fmaf(s1, inv, lx.y));
}

__global__ __launch_bounds__(256) void k_edge_ln(
    const float* __restrict__ lnew, const float* __restrict__ edge_attr,
    const float* __restrict__ g_edge, const float* __restrict__ beta_edge,
    float* __restrict__ out_edge, int En)
{
    const int wave = threadIdx.x >> 6, lane = threadIdx.x & 63;
    const int e = blockIdx.x * 4 + wave;
    if (e >= En) return;
    const size_t rb = (size_t)e * 128 + lane * 2;
    float2 lv = *(const float2*)&lnew[rb];
    float2 ea = *(const float2*)&edge_attr[rb];
    float t0 = ea.x + lv.x, t1 = ea.y + lv.y;
    float s = t0 + t1, sq = t0 * t0 + t1 * t1;
    #pragma unroll
    for (int o = 32; o; o >>= 1) { s += __shfl_xor(s, o); sq += __shfl_xor(sq, o); }
    float mean = s * (1.f / 128.f);
    float var  = sq * (1.f / 128.f) - mean * mean;
    float r = rsqrtf(var + 1e-5f);
    int j0 = lane * 2;
    float o0 = (t0 - mean) * r * g_edge[j0]     + beta_edge[j0];
    float o1 = (t1 - mean) * r * g_edge[j0 + 1] + beta_edge[j0 + 1];
    *(float2*)&out_edge[rb] = make_float2(o0, o1);
}

// ---------------- K3: gate GEMM -> gated row at pos_at[e] ----------------
// BF path: A-fragment loads cover the block's full 128x128 enew tile exactly
// once; each fragment is stored to LDS as it is loaded (intra-wave sharing
// only). Epilogue reads ev from LDS and overwrites in place with gated value.
template <bool BF>
__global__ __launch_bounds__(256) void k_gate_csr(
    const short* __restrict__ EinB, const float* __restrict__ EinF,
    const short* __restrict__ Wp, const float* __restrict__ bg,
    const int* __restrict__ pos_at, short* __restrict__ gated, int En)
{
    __shared__ __align__(16) short sh[128][136];
    const int tid = threadIdx.x;
    const int ln = tid & 63, wv = tid >> 6;
    const int l15 = ln & 15, lhi = ln >> 4;
    const int eb = blockIdx.x * 128 + wv * 32;
    const s16x8* Bv = (const s16x8*)Wp;

    int rowi[2];
    #pragma unroll
    for (int mt = 0; mt < 2; ++mt) {
        int e = eb + mt * 16 + l15;
        rowi[mt] = e < En ? e : En - 1;
    }

    f32x4 acc[2][8];
    #pragma unroll
    for (int m = 0; m < 2; ++m)
        #pragma unroll
        for (int n = 0; n < 8; ++n) acc[m][n] = (f32x4){0.f, 0.f, 0.f, 0.f};

    #pragma unroll 2
    for (int kt = 0; kt < 4; ++kt) {
        int ko = kt * 32 + lhi * 8;
        s16x8 a[2];
        #pragma unroll
        for (int mt = 0; mt < 2; ++mt) {
            if (BF) {
                a[mt] = *(const s16x8*)(EinB + (size_t)rowi[mt] * 128 + ko);
                *(s16x8*)&sh[wv * 32 + mt * 16 + l15][ko] = a[mt];   // tile->LDS
            } else {
                const float* p = EinF + (size_t)rowi[mt] * 128 + ko;
                float buf[8];
                *(float4*)&buf[0] = *(const float4*)p;
                *(float4*)&buf[4] = *(const float4*)(p + 4);
                a[mt] = pack8(buf);
            }
        }
        const s16x8* brow = Bv + (size_t)(kt * 4 + lhi) * 128 + l15;
        #pragma unroll
        for (int nt = 0; nt < 8; ++nt) {
            s16x8 b = brow[nt * 16];
            acc[0][nt] = __builtin_amdgcn_mfma_f32_16x16x32_bf16(a[0], b, acc[0][nt], 0, 0, 0);
            acc[1][nt] = __builtin_amdgcn_mfma_f32_16x16x32_bf16(a[1], b, acc[1][nt], 0, 0, 0);
        }
    }

    #pragma unroll
    for (int nt = 0; nt < 8; ++nt) {
        int col = nt * 16 + l15;
        float bs = bg[col];
        #pragma unroll
        for (int mt = 0; mt < 2; ++mt)
            #pragma unroll
            for (int r = 0; r < 4; ++r) {
                int row = wv * 32 + mt * 16 + lhi * 4 + r;
                int e = eb + mt * 16 + lhi * 4 + r;
                int ec = e < En ? e : En - 1;
                float g = 1.f / (1.f + __expf(-(acc[mt][nt][r] + bs)));
                float ev = BF ? bf2f((unsigned short)sh[row][col])
                              : EinF[(size_t)ec * 128 + col];
                sh[row][col] = f2bf(g * ev);
            }
    }
    __syncthreads();
    #pragma unroll
    for (int i = 0; i < 8; ++i) {
        int c = tid + i * 256;
        int row = c >> 4, q = c & 15;
        int e = blockIdx.x * 128 + row;
        if (e < En) {
            int p = pos_at[e];
            *(s16x8*)&gated[(size_t)p * 128 + q * 8] = *(const s16x8*)&sh[row][q * 8];
        }
    }
}

// ---------------- K4: contiguous atom aggregation (4 nodes/wave, 16B/lane) ----------------
template <bool BF_OUT>
__global__ __launch_bounds__(256) void k_atom_gather(
    const short* __restrict__ gated, const int* __restrict__ off,
    float* __restrict__ aggf, short* __restrict__ aggb, int Nn)
{
    const int wave = threadIdx.x >> 6, lane = threadIdx.x & 63;
    const int sub = lane >> 4, l = lane & 15;
    const int n = blockIdx.x * 16 + wave * 4 + sub;
    if (n >= Nn) return;
    const int o0 = off[n], o1 = off[n + 1];
    const int cnt = o1 - o0;
    const short* base = gated + (size_t)o0 * 128 + l * 8;
    float s[8];
    #pragma unroll
    for (int k = 0; k < 8; ++k) s[k] = 0.f;
    for (int j = 0; j < cnt; ++j) {
        s16x8 u = *(const s16x8*)(base + (size_t)j * 128);
        #pragma unroll
        for (int k = 0; k < 8; ++k) s[k] += bf2f((unsigned short)u[k]);
    }
    const size_t rb = (size_t)n * 128 + l * 8;
    if (BF_OUT) {
        s16x8 ub;
        #pragma unroll
        for (int k = 0; k < 8; ++k) ub[k] = f2bf(s[k]);
        *(s16x8*)&aggb[rb] = ub;
    } else {
        *(float4*)&aggf[rb]     = make_float4(s[0], s[1], s[2], s[3]);
        *(float4*)&aggf[rb + 4] = make_float4(s[4], s[5], s[6], s[7]);
    }
}

// ---------------- K5: atom GEMM + residual + in-register LN ----------------
template <bool AGGBF>
__global__ __launch_bounds__(256) void k_atom_mfma(
    const float* __restrict__ x, const float* __restrict__ aggf,
    const short* __restrict__ aggb,
    const short* __restrict__ Wp, const float* __restrict__ ba,
    const float* __restrict__ gn, const float* __restrict__ bn,
    float* __restrict__ out, int Nn)
{
    const int tid = threadIdx.x;
    const int ln = tid & 63, wv = tid >> 6;
    const int l15 = ln & 15, lhi = ln >> 4;
    const int nb = blockIdx.x * 128 + wv * 32;
    const s16x8* Bv = (const s16x8*)Wp;

    const float* xp[2];
    size_t nc[2];
    #pragma unroll
    for (int mt = 0; mt < 2; ++mt) {
        int n = nb + mt * 16 + l15;
        nc[mt] = (size_t)(n < Nn ? n : Nn - 1) * 128;
        xp[mt] = x + nc[mt];
    }

    f32x4 acc[2][8];
    #pragma unroll
    for (int m = 0; m < 2; ++m)
        #pragma unroll
        for (int n = 0; n < 8; ++n) acc[m][n] = (f32x4){0.f, 0.f, 0.f, 0.f};

    #pragma unroll 2
    for (int kt = 0; kt < 8; ++kt) {
        int ko = (kt & 3) * 32 + lhi * 8;
        s16x8 a[2];
        #pragma unroll
        for (int mt = 0; mt < 2; ++mt) {
            if (kt < 4) {
                const float* p = xp[mt] + ko;
                float buf[8];
                *(float4*)&buf[0] = *(const float4*)p;
                *(float4*)&buf[4] = *(const float4*)(p + 4);
                a[mt] = pack8(buf);
            } else if (AGGBF) {
                a[mt] = *(const s16x8*)(aggb + nc[mt] + ko);
            } else {
                const float* p = aggf + nc[mt] + ko;
                float buf[8];
                *(float4*)&buf[0] = *(const float4*)p;
                *(float4*)&buf[4] = *(const float4*)(p + 4);
                a[mt] = pack8(buf);
            }
        }
        const s16x8* brow = Bv + (size_t)(kt * 4 + lhi) * 128 + l15;
        #pragma unroll
        for (int nt = 0; nt < 8; ++nt) {
            s16x8 b = brow[nt * 16];
            acc[0][nt] = __builtin_amdgcn_mfma_f32_16x16x32_bf16(a[0], b, acc[0][nt], 0, 0, 0);
            acc[1][nt] = __builtin_amdgcn_mfma_f32_16x16x32_bf16(a[1], b, acc[1][nt], 0, 0, 0);
        }
    }

    #pragma unroll
    for (int mt = 0; mt < 2; ++mt)
        #pragma unroll
        for (int r = 0; r < 4; ++r) {
            int n = nb + mt * 16 + lhi * 4 + r;
            size_t nr = (size_t)(n < Nn ? n : 0) * 128;
            float s = 0.f, sq = 0.f;
            #pragma unroll
            for (int nt = 0; nt < 8; ++nt) {
                int col = nt * 16 + l15;
                float v = acc[mt][nt][r] + ba[col];
                float h = v / (1.f + __expf(-v));
                float t = x[nr + col] + h;
                acc[mt][nt][r] = t;
                s += t; sq += t * t;
            }
            #pragma unroll
            for (int o = 8; o; o >>= 1) {
                s  += __shfl_xor(s, o);
                sq += __shfl_xor(sq, o);
            }
            float mean = s * (1.f / 128.f);
            float var  = sq * (1.f / 128.f) - mean * mean;
            float rstd = rsqrtf(var + 1e-5f);
            if (n < Nn) {
                #pragma unroll
                for (int nt = 0; nt < 8; ++nt) {
                    int col = nt * 16 + l15;
                    float o = (acc[mt][nt][r] - mean) * rstd * gn[col] + bn[col];
                    out[(size_t)n * 128 + col] = o;
                }
            }
        }
}

// ---------------------------------------------------------------------------
extern "C" void kernel_launch(void* const* d_in, const int* in_sizes, int n_in,
                              void* d_out, int out_size, void* d_ws, size_t ws_size,
                              hipStream_t stream) {
    const float* x          = (const float*)d_in[0];
    const float* edge_attr  = (const float*)d_in[1];
    const float* lg_x       = (const float*)d_in[2];
    const float* lg_ea      = (const float*)d_in[3];
    const float* W_line     = (const float*)d_in[4];
    const float* b_line     = (const float*)d_in[5];
    const float* W_gate     = (const float*)d_in[6];
    const float* b_gate     = (const float*)d_in[7];
    const float* W_atom     = (const float*)d_in[8];
    const float* b_atom     = (const float*)d_in[9];
    const float* g_node     = (const float*)d_in[10];
    const float* beta_node  = (const float*)d_in[11];
    const float* g_edge     = (const float*)d_in[12];
    const float* beta_edge  = (const float*)d_in[13];
    const int*   edge_index    = (const int*)d_in[14];
    const int*   lg_edge_index = (const int*)d_in[15];

    const int Nn  = in_sizes[0] / 128;
    const int En  = in_sizes[1] / 128;
    const int LEn = in_sizes[3];

    float* out_x    = (float*)d_out;
    float* out_edge = out_x + (size_t)Nn * 128;
    float* out_lg   = out_edge + (size_t)En * 128;

    const int* lg_src = lg_edge_index;
    const int* lg_dst = lg_edge_index + LEn;
    const int* col    = edge_index + En;

    // ws layout
    short* wp_line = (short*)d_ws;            // 32768 shorts
    short* wp_gate = wp_line + 32768;         // 16384
    short* wp_atom = wp_gate + 16384;         // 32768
    int* ip = (int*)(wp_atom + 32768);
    int* off_lg  = ip;  ip += En + 1;
    int* deg_lg  = ip;  ip += En;             // deg+cur contiguous (1 memset)
    int* cur_lg  = ip;  ip += En;
    int* perm_lg = ip;  ip += LEn;
    int* bsum_lg = ip;  ip += 1024;
    int* off_at  = ip;  ip += Nn + 1;
    int* deg_at  = ip;  ip += Nn;
    int* cur_at  = ip;  ip += Nn;
    int* pos_at  = ip;  ip += En;
    int* bsum_at = ip;  ip += 1024;
    short* lgx_bf = (short*)(((uintptr_t)ip + 15) & ~(uintptr_t)15);
    short* bufA   = lgx_bf + (size_t)En * 128;       // msg, then gated (256 MB)
    short* agg_bf = bufA + (size_t)En * 128;         // 51 MB
    const size_t need_A = ((uintptr_t)(agg_bf + (size_t)Nn * 128)) - (uintptr_t)d_ws;
    const bool tierA = ws_size >= need_A;

    hipMemsetAsync(deg_lg, 0, (size_t)En * 8, stream);
    hipMemsetAsync(deg_at, 0, (size_t)Nn * 8, stream);

    const int nmax = LEn > En ? LEn : En;
    const int cvtBlocks = 2048;
    const int histBlocks = (nmax + 255) / 256;
    k_prep<<<40 + cvtBlocks + histBlocks, 256, 0, stream>>>(
        W_line, W_gate, W_atom, wp_line, wp_gate, wp_atom,
        lg_x, lgx_bf, (long)En * 16,
        lg_dst, deg_lg, LEn, col, deg_at, En, cvtBlocks);

    const int nb_lg = (En + SCAN_CHUNK - 1) / SCAN_CHUNK;
    const int nb_at = (Nn + SCAN_CHUNK - 1) / SCAN_CHUNK;
    k_scan_block2<<<nb_lg + nb_at, 256, 0, stream>>>(
        deg_lg, En, off_lg, bsum_lg, nb_lg, deg_at, Nn, off_at, bsum_at);
    k_scan_bsum2<<<1, 128, 0, stream>>>(bsum_lg, nb_lg, bsum_at, nb_at);
    const int sa_max = En > Nn ? En : Nn;
    k_scan_add2<<<(sa_max + 255) / 256, 256, 0, stream>>>(
        off_lg, bsum_lg, En, LEn, off_at, bsum_at, Nn, En);
    k_fill2<<<(nmax + 255) / 256, 256, 0, stream>>>(
        lg_dst, off_lg, cur_lg, perm_lg, LEn, col, off_at, cur_at, pos_at, En);

    if (tierA) {
        short* msg = bufA;
        k_line_csr<<<(LEn + 127) / 128, 256, 0, stream>>>(
            lgx_bf, lg_ea, wp_line, W_line, b_line, lg_src, lg_dst, perm_lg, msg, LEn);
        short* enew_bf = lgx_bf;             // same-thread same-index RAW only (r8-proven)
        k_lg_edge_fused<<<(En + 15) / 16, 256, 0, stream>>>(
            msg, lgx_bf, edge_attr, off_lg, g_edge, beta_edge,
            out_lg, out_edge, enew_bf, En);
        short* gated = bufA;                 // msg dead after fused gather
        k_gate_csr<true><<<(En + 127) / 128, 256, 0, stream>>>(
            enew_bf, nullptr, wp_gate, b_gate, pos_at, gated, En);
        k_atom_gather<true><<<(Nn + 15) / 16, 256, 0, stream>>>(
            gated, off_at, nullptr, agg_bf, Nn);
        k_atom_mfma<true><<<(Nn + 127) / 128, 256, 0, stream>>>(
            x, nullptr, agg_bf, wp_atom, b_atom, g_node, beta_node, out_x, Nn);
    } else {
        short* msgB = (short*)out_edge;      // scratch in d_out, overwritten later
        k_line_csr<<<(LEn + 127) / 128, 256, 0, stream>>>(
            lgx_bf, lg_ea, wp_line, W_line, b_line, lg_src, lg_dst, perm_lg, msgB, LEn);
        k_lg_gather<<<(En + 3) / 4, 256, 0, stream>>>(msgB, lg_x, off_lg, out_lg, En);
        k_edge_ln<<<(En + 3) / 4, 256, 0, stream>>>(
            out_lg, edge_attr, g_edge, beta_edge, out_edge, En);
        short* gatedB = lgx_bf;              // lgx_bf dead in tier B here
        k_gate_csr<false><<<(En + 127) / 128, 256, 0, stream>>>(
            nullptr, out_edge, wp_gate, b_gate, pos_at, gatedB, En);
        k_atom_gather<false><<<(Nn + 15) / 16, 256, 0, stream>>>(
            gatedB, off_at, out_x, nullptr, Nn);
        k_atom_mfma<false><<<(Nn + 127) / 128, 256, 0, stream>>>(
            x, out_x, nullptr, wp_atom, b_atom, g_node, beta_node, out_x, Nn);
    }
}

// Round 13
// 1441.717 us; speedup vs baseline: 1.0169x; 1.0169x over previous
//
#include <hip/hip_runtime.h>

// ---------------------------------------------------------------------------
// EdgeGatedConv — round 13: exact revert to r11 (best measured: 1446.7µs).
//   r12 post-mortem: 16B/lane segment kernels (4 edges/wave) added Poisson-
//   degree divergence (max-of-4 vs max-of-2) and regressed +19µs. Reverted.
//   Pipeline (tier A):
//   K1 k_line_csr:      GEMM (CSR order via perm_lg) -> msg[p] sequential
//   K2 k_lg_edge_fused: out_lg = bf(lg_x)+mean(msg); out_edge =
//                       LN(edge_attr+out_lg); enew_bf = bf16(out_edge)
//   K3 k_gate_csr<BF>:  gate GEMM (A-frags->LDS); gated row at pos_at[e]
//   K4 k_atom_gather:   agg_bf[n] = sum(gated[o0:o1])  (contiguous, bf16)
//   K5 k_atom_mfma:     h=silu([x,agg]@Wa+b); out_x = LN(x+h)
// MFMA 16x16x32 bf16: A row=lane&15, B col=lane&15, k=(lane>>4)*8+j both ops;
// C/D col=lane&15, row=(lane>>4)*4+reg.
// ---------------------------------------------------------------------------

typedef __attribute__((ext_vector_type(8))) short s16x8;
typedef __attribute__((ext_vector_type(4))) float f32x4;

#define SCAN_CHUNK 2048

__device__ __forceinline__ short f2bf(float f) {
    unsigned u = __float_as_uint(f);
    u += 0x7FFF + ((u >> 16) & 1);
    return (short)(u >> 16);
}
__device__ __forceinline__ float bf2f(unsigned short h) {
    return __uint_as_float(((unsigned)h) << 16);
}
__device__ __forceinline__ s16x8 pack8(const float* v) {
    s16x8 r;
    #pragma unroll
    for (int j = 0; j < 8; ++j) r[j] = f2bf(v[j]);
    return r;
}

// ---------------- merged prep: pack3 + cvt + hist2 ----------------
__global__ __launch_bounds__(256) void k_prep(
    const float* __restrict__ Wl, const float* __restrict__ Wg,
    const float* __restrict__ Wa,
    short* __restrict__ Pl, short* __restrict__ Pg, short* __restrict__ Pa,
    const float* __restrict__ lgx, short* __restrict__ lgx_bf, long n8,
    const int* __restrict__ idx1, int* __restrict__ deg1, int n1,
    const int* __restrict__ idx2, int* __restrict__ deg2, int n2,
    int cvtBlocks)
{
    const int b = blockIdx.x;
    if (b < 40) {                              // weight pack
        int c = b * 256 + threadIdx.x;
        const float* W; short* P; int cc;
        if (c < 4096)       { W = Wl; P = Pl; cc = c; }
        else if (c < 6144)  { W = Wg; P = Pg; cc = c - 4096; }
        else if (c < 10240) { W = Wa; P = Pa; cc = c - 6144; }
        else return;
        int g = cc >> 7, col = cc & 127, k0 = g * 8;
        s16x8 v;
        #pragma unroll
        for (int j = 0; j < 8; ++j) v[j] = f2bf(W[(size_t)(k0 + j) * 128 + col]);
        ((s16x8*)P)[cc] = v;
    } else if (b < 40 + cvtBlocks) {           // lg_x -> bf16
        long i = (long)(b - 40) * 256 + threadIdx.x;
        const long stride = (long)cvtBlocks * 256;
        for (; i < n8; i += stride) {
            float buf[8];
            *(float4*)&buf[0] = ((const float4*)lgx)[2 * i];
            *(float4*)&buf[4] = ((const float4*)lgx)[2 * i + 1];
            ((s16x8*)lgx_bf)[i] = pack8(buf);
        }
    } else {                                   // dual histogram
        int i = (b - 40 - cvtBlocks) * 256 + threadIdx.x;
        if (i < n1) atomicAdd(&deg1[idx1[i]], 1);
        if (i < n2) atomicAdd(&deg2[idx2[i]], 1);
    }
}

// ---------------- CSR build ----------------
__global__ __launch_bounds__(256) void k_scan_block2(
    const int* __restrict__ in1, int n1, int* __restrict__ out1, int* __restrict__ bsum1, int nb1,
    const int* __restrict__ in2, int n2, int* __restrict__ out2, int* __restrict__ bsum2)
{
    __shared__ int ts[256];
    int b = blockIdx.x;
    const int* in; int n; int* out; int* bsum;
    if (b < nb1) { in = in1; n = n1; out = out1; bsum = bsum1; }
    else         { in = in2; n = n2; out = out2; bsum = bsum2; b -= nb1; }
    const int t = threadIdx.x;
    const int base = b * SCAN_CHUNK + t * 8;
    int v[8]; int s = 0;
    #pragma unroll
    for (int i = 0; i < 8; ++i) { v[i] = (base + i < n) ? in[base + i] : 0; s += v[i]; }
    ts[t] = s;
    __syncthreads();
    int x = s;
    for (int off = 1; off < 256; off <<= 1) {
        int y = (t >= off) ? ts[t - off] : 0;
        __syncthreads();
        x += y; ts[t] = x;
        __syncthreads();
    }
    if (t == 255) bsum[b] = x;
    int run = x - s;
    #pragma unroll
    for (int i = 0; i < 8; ++i) {
        if (base + i < n) out[base + i] = run;
        run += v[i];
    }
}

__global__ void k_scan_bsum2(int* __restrict__ b1, int nb1,
                             int* __restrict__ b2, int nb2) {  // 128 thr = 2 waves
    const int lane = threadIdx.x & 63;
    int* bsum = (threadIdx.x < 64) ? b1 : b2;
    const int nb  = (threadIdx.x < 64) ? nb1 : nb2;
    int carry = 0;
    for (int base = 0; base < nb; base += 64) {
        int i = base + lane;
        int v = (i < nb) ? bsum[i] : 0;
        int inc = v;
        #pragma unroll
        for (int off = 1; off < 64; off <<= 1) {
            int t = __shfl_up(inc, off);
            if (lane >= off) inc += t;
        }
        if (i < nb) bsum[i] = inc - v + carry;
        carry += __shfl(inc, 63);
    }
}

__global__ __launch_bounds__(256) void k_scan_add2(
    int* __restrict__ off1, const int* __restrict__ bsum1, int n1, int ne1,
    int* __restrict__ off2, const int* __restrict__ bsum2, int n2, int ne2)
{
    int i = blockIdx.x * 256 + threadIdx.x;
    if (i < n1) off1[i] += bsum1[i / SCAN_CHUNK];
    if (i < n2) off2[i] += bsum2[i / SCAN_CHUNK];
    if (i == 0) { off1[n1] = ne1; off2[n2] = ne2; }
}

// graph1: perm (pos -> edge); graph2: pos (edge -> pos)
__global__ __launch_bounds__(256) void k_fill2(
    const int* __restrict__ idx1, const int* __restrict__ off1,
    int* __restrict__ cur1, int* __restrict__ perm1, int n1,
    const int* __restrict__ idx2, const int* __restrict__ off2,
    int* __restrict__ cur2, int* __restrict__ pos2, int n2)
{
    int i = blockIdx.x * 256 + threadIdx.x;
    if (i < n1) {
        int s = idx1[i];
        int p = atomicAdd(&cur1[s], 1);
        perm1[off1[s] + p] = i;
    }
    if (i < n2) {
        int s = idx2[i];
        int p = atomicAdd(&cur2[s], 1);
        pos2[i] = off2[s] + p;
    }
}

// ---------------- K1: line GEMM in CSR order -> msg[p] sequential ----------------
__global__ __launch_bounds__(256) void k_line_csr(
    const short* __restrict__ lgx_bf, const float* __restrict__ lg_ea,
    const short* __restrict__ Wp, const float* __restrict__ W_line,
    const float* __restrict__ b_line,
    const int* __restrict__ lg_src, const int* __restrict__ lg_dst,
    const int* __restrict__ perm_lg,
    short* __restrict__ msg, int LEn)
{
    __shared__ __align__(16) short sh[128][136];
    const int tid = threadIdx.x;
    const int ln = tid & 63, wv = tid >> 6;
    const int l15 = ln & 15, lhi = ln >> 4;
    const int pb = blockIdx.x * 128 + wv * 32;
    const s16x8* Bv = (const s16x8*)Wp;

    const short *sp[2], *dp[2];
    #pragma unroll
    for (int mt = 0; mt < 2; ++mt) {
        int p = pb + mt * 16 + l15;
        int pc = p < LEn ? p : LEn - 1;
        int e = perm_lg[pc];
        sp[mt] = lgx_bf + (size_t)lg_src[e] * 128;
        dp[mt] = lgx_bf + (size_t)lg_dst[e] * 128;   // monotone in CSR order
    }

    f32x4 acc[2][8];
    #pragma unroll
    for (int m = 0; m < 2; ++m)
        #pragma unroll
        for (int n = 0; n < 8; ++n) acc[m][n] = (f32x4){0.f, 0.f, 0.f, 0.f};

    #pragma unroll 2
    for (int kt = 0; kt < 8; ++kt) {
        int ko = (kt & 3) * 32 + lhi * 8;
        s16x8 a[2];
        #pragma unroll
        for (int mt = 0; mt < 2; ++mt)
            a[mt] = *(const s16x8*)(((kt < 4) ? sp[mt] : dp[mt]) + ko);
        const s16x8* brow = Bv + (size_t)(kt * 4 + lhi) * 128 + l15;
        #pragma unroll
        for (int nt = 0; nt < 8; ++nt) {
            s16x8 b = brow[nt * 16];
            acc[0][nt] = __builtin_amdgcn_mfma_f32_16x16x32_bf16(a[0], b, acc[0][nt], 0, 0, 0);
            acc[1][nt] = __builtin_amdgcn_mfma_f32_16x16x32_bf16(a[1], b, acc[1][nt], 0, 0, 0);
        }
    }

    float eav[2][4];
    #pragma unroll
    for (int mt = 0; mt < 2; ++mt)
        #pragma unroll
        for (int r = 0; r < 4; ++r) {
            int p = pb + mt * 16 + lhi * 4 + r;
            int pc = p < LEn ? p : LEn - 1;
            eav[mt][r] = lg_ea[perm_lg[pc]];
        }

    #pragma unroll
    for (int nt = 0; nt < 8; ++nt) {
        int col = nt * 16 + l15;
        float wl = W_line[(size_t)256 * 128 + col];
        float bs = b_line[col];
        #pragma unroll
        for (int mt = 0; mt < 2; ++mt)
            #pragma unroll
            for (int r = 0; r < 4; ++r) {
                float v = acc[mt][nt][r] + bs + wl * eav[mt][r];
                float s = v / (1.f + __expf(-v));
                sh[wv * 32 + mt * 16 + lhi * 4 + r][col] = f2bf(s);
            }
    }
    __syncthreads();
    #pragma unroll
    for (int i = 0; i < 8; ++i) {
        int c = tid + i * 256;
        int row = c >> 4, q = c & 15;
        int p = blockIdx.x * 128 + row;
        if (p < LEn)
            *(s16x8*)&msg[(size_t)p * 128 + q * 8] = *(const s16x8*)&sh[row][q * 8];
    }
}

// ---------------- K2: fused gather-mean + residual + edge LN (2 edges/wave) ----------------
__global__ __launch_bounds__(256) void k_lg_edge_fused(
    const short* __restrict__ msg, const short* __restrict__ lgx_bf,
    const float* __restrict__ edge_attr, const int* __restrict__ off,
    const float* __restrict__ g_edge, const float* __restrict__ beta_edge,
    float* __restrict__ out_lg, float* __restrict__ out_edge,
    short* __restrict__ enew_bf, int En)
{
    const int wave = threadIdx.x >> 6, lane = threadIdx.x & 63;
    const int half = lane >> 5, l = lane & 31;
    const int e = blockIdx.x * 8 + wave * 2 + half;
    if (e >= En) return;
    const int o0 = off[e], o1 = off[e + 1];
    const int cnt = o1 - o0;
    const short* mbase = msg + (size_t)o0 * 128 + l * 4;
    float s0 = 0.f, s1 = 0.f, s2 = 0.f, s3 = 0.f;
    for (int j = 0; j < cnt; ++j) {
        ushort4 u = *(const ushort4*)(mbase + (size_t)j * 128);
        s0 += bf2f(u.x); s1 += bf2f(u.y); s2 += bf2f(u.z); s3 += bf2f(u.w);
    }
    const float inv = 1.f / fmaxf((float)cnt, 1.f);
    const size_t rb = (size_t)e * 128 + l * 4;
    ushort4 lxu = *(const ushort4*)&lgx_bf[rb];
    float l0 = fmaf(s0, inv, bf2f(lxu.x));
    float l1 = fmaf(s1, inv, bf2f(lxu.y));
    float l2 = fmaf(s2, inv, bf2f(lxu.z));
    float l3 = fmaf(s3, inv, bf2f(lxu.w));
    *(float4*)&out_lg[rb] = make_float4(l0, l1, l2, l3);

    float4 ea = *(const float4*)&edge_attr[rb];
    float t0 = ea.x + l0, t1 = ea.y + l1, t2 = ea.z + l2, t3 = ea.w + l3;
    float s = t0 + t1 + t2 + t3;
    float sq = t0 * t0 + t1 * t1 + t2 * t2 + t3 * t3;
    #pragma unroll
    for (int o = 16; o; o >>= 1) {             // reduce within 32-lane half
        s  += __shfl_xor(s, o);
        sq += __shfl_xor(sq, o);
    }
    float mean = s * (1.f / 128.f);
    float var  = sq * (1.f / 128.f) - mean * mean;
    float r = rsqrtf(var + 1e-5f);
    int j0 = l * 4;
    float4 gg = *(const float4*)&g_edge[j0];
    float4 bb = *(const float4*)&beta_edge[j0];
    float e0 = fmaf((t0 - mean) * r, gg.x, bb.x);
    float e1 = fmaf((t1 - mean) * r, gg.y, bb.y);
    float e2 = fmaf((t2 - mean) * r, gg.z, bb.z);
    float e3 = fmaf((t3 - mean) * r, gg.w, bb.w);
    *(float4*)&out_edge[rb] = make_float4(e0, e1, e2, e3);
    if (enew_bf) {
        ushort4 ub = make_ushort4((unsigned short)f2bf(e0), (unsigned short)f2bf(e1),
                                  (unsigned short)f2bf(e2), (unsigned short)f2bf(e3));
        *(ushort4*)&enew_bf[rb] = ub;
    }
}

// ---------------- tier-B: unfused gather + LN ----------------
__global__ __launch_bounds__(256) void k_lg_gather(
    const short* __restrict__ msg, const float* __restrict__ lg_x,
    const int* __restrict__ off, float* __restrict__ out_lg, int En)
{
    const int wave = threadIdx.x >> 6, lane = threadIdx.x & 63;
    const int e = blockIdx.x * 4 + wave;
    if (e >= En) return;
    const int o0 = off[e], o1 = off[e + 1];
    const int cnt = o1 - o0;
    const short* base = msg + (size_t)o0 * 128 + lane * 2;
    float s0 = 0.f, s1 = 0.f;
    for (int j = 0; j < cnt; ++j) {
        ushort2 u = *(const ushort2*)(base + (size_t)j * 128);
        s0 += bf2f(u.x); s1 += bf2f(u.y);
    }
    const float inv = 1.f / fmaxf((float)cnt, 1.f);
    const size_t rb = (size_t)e * 128 + lane * 2;
    float2 lx = *(const float2*)&lg_x[rb];
    *(float2*)&out_lg[rb] = make_float2(fmaf(s0, inv, lx.x), fmaf(s1, inv, lx.y));
}

__global__ __launch_bounds__(256) void k_edge_ln(
    const float* __restrict__ lnew, const float* __restrict__ edge_attr,
    const float* __restrict__ g_edge, const float* __restrict__ beta_edge,
    float* __restrict__ out_edge, int En)
{
    const int wave = threadIdx.x >> 6, lane = threadIdx.x & 63;
    const int e = blockIdx.x * 4 + wave;
    if (e >= En) return;
    const size_t rb = (size_t)e * 128 + lane * 2;
    float2 lv = *(const float2*)&lnew[rb];
    float2 ea = *(const float2*)&edge_attr[rb];
    float t0 = ea.x + lv.x, t1 = ea.y + lv.y;
    float s = t0 + t1, sq = t0 * t0 + t1 * t1;
    #pragma unroll
    for (int o = 32; o; o >>= 1) { s += __shfl_xor(s, o); sq += __shfl_xor(sq, o); }
    float mean = s * (1.f / 128.f);
    float var  = sq * (1.f / 128.f) - mean * mean;
    float r = rsqrtf(var + 1e-5f);
    int j0 = lane * 2;
    float o0 = (t0 - mean) * r * g_edge[j0]     + beta_edge[j0];
    float o1 = (t1 - mean) * r * g_edge[j0 + 1] + beta_edge[j0 + 1];
    *(float2*)&out_edge[rb] = make_float2(o0, o1);
}

// ---------------- K3: gate GEMM -> gated row at pos_at[e] ----------------
// BF path: A-fragment loads cover the block's full 128x128 enew tile exactly
// once; each fragment is stored to LDS as it is loaded (intra-wave sharing
// only). Epilogue reads ev from LDS and overwrites in place with gated value.
template <bool BF>
__global__ __launch_bounds__(256) void k_gate_csr(
    const short* __restrict__ EinB, const float* __restrict__ EinF,
    const short* __restrict__ Wp, const float* __restrict__ bg,
    const int* __restrict__ pos_at, short* __restrict__ gated, int En)
{
    __shared__ __align__(16) short sh[128][136];
    const int tid = threadIdx.x;
    const int ln = tid & 63, wv = tid >> 6;
    const int l15 = ln & 15, lhi = ln >> 4;
    const int eb = blockIdx.x * 128 + wv * 32;
    const s16x8* Bv = (const s16x8*)Wp;

    int rowi[2];
    #pragma unroll
    for (int mt = 0; mt < 2; ++mt) {
        int e = eb + mt * 16 + l15;
        rowi[mt] = e < En ? e : En - 1;
    }

    f32x4 acc[2][8];
    #pragma unroll
    for (int m = 0; m < 2; ++m)
        #pragma unroll
        for (int n = 0; n < 8; ++n) acc[m][n] = (f32x4){0.f, 0.f, 0.f, 0.f};

    #pragma unroll 2
    for (int kt = 0; kt < 4; ++kt) {
        int ko = kt * 32 + lhi * 8;
        s16x8 a[2];
        #pragma unroll
        for (int mt = 0; mt < 2; ++mt) {
            if (BF) {
                a[mt] = *(const s16x8*)(EinB + (size_t)rowi[mt] * 128 + ko);
                *(s16x8*)&sh[wv * 32 + mt * 16 + l15][ko] = a[mt];   // tile->LDS
            } else {
                const float* p = EinF + (size_t)rowi[mt] * 128 + ko;
                float buf[8];
                *(float4*)&buf[0] = *(const float4*)p;
                *(float4*)&buf[4] = *(const float4*)(p + 4);
                a[mt] = pack8(buf);
            }
        }
        const s16x8* brow = Bv + (size_t)(kt * 4 + lhi) * 128 + l15;
        #pragma unroll
        for (int nt = 0; nt < 8; ++nt) {
            s16x8 b = brow[nt * 16];
            acc[0][nt] = __builtin_amdgcn_mfma_f32_16x16x32_bf16(a[0], b, acc[0][nt], 0, 0, 0);
            acc[1][nt] = __builtin_amdgcn_mfma_f32_16x16x32_bf16(a[1], b, acc[1][nt], 0, 0, 0);
        }
    }

    #pragma unroll
    for (int nt = 0; nt < 8; ++nt) {
        int col = nt * 16 + l15;
        float bs = bg[col];
        #pragma unroll
        for (int mt = 0; mt < 2; ++mt)
            #pragma unroll
            for (int r = 0; r < 4; ++r) {
                int row = wv * 32 + mt * 16 + lhi * 4 + r;
                int e = eb + mt * 16 + lhi * 4 + r;
                int ec = e < En ? e : En - 1;
                float g = 1.f / (1.f + __expf(-(acc[mt][nt][r] + bs)));
                float ev = BF ? bf2f((unsigned short)sh[row][col])
                              : EinF[(size_t)ec * 128 + col];
                sh[row][col] = f2bf(g * ev);
            }
    }
    __syncthreads();
    #pragma unroll
    for (int i = 0; i < 8; ++i) {
        int c = tid + i * 256;
        int row = c >> 4, q = c & 15;
        int e = blockIdx.x * 128 + row;
        if (e < En) {
            int p = pos_at[e];
            *(s16x8*)&gated[(size_t)p * 128 + q * 8] = *(const s16x8*)&sh[row][q * 8];
        }
    }
}

// ---------------- K4: contiguous atom aggregation (2 nodes/wave) ----------------
template <bool BF_OUT>
__global__ __launch_bounds__(256) void k_atom_gather(
    const short* __restrict__ gated, const int* __restrict__ off,
    float* __restrict__ aggf, short* __restrict__ aggb, int Nn)
{
    const int wave = threadIdx.x >> 6, lane = threadIdx.x & 63;
    const int half = lane >> 5, l = lane & 31;
    const int n = blockIdx.x * 8 + wave * 2 + half;
    if (n >= Nn) return;
    const int o0 = off[n], o1 = off[n + 1];
    const int cnt = o1 - o0;
    const short* base = gated + (size_t)o0 * 128 + l * 4;
    float s0 = 0.f, s1 = 0.f, s2 = 0.f, s3 = 0.f;
    for (int j = 0; j < cnt; ++j) {
        ushort4 u = *(const ushort4*)(base + (size_t)j * 128);
        s0 += bf2f(u.x); s1 += bf2f(u.y); s2 += bf2f(u.z); s3 += bf2f(u.w);
    }
    const size_t rb = (size_t)n * 128 + l * 4;
    if (BF_OUT) {
        ushort4 ub = make_ushort4((unsigned short)f2bf(s0), (unsigned short)f2bf(s1),
                                  (unsigned short)f2bf(s2), (unsigned short)f2bf(s3));
        *(ushort4*)&aggb[rb] = ub;
    } else {
        *(float4*)&aggf[rb] = make_float4(s0, s1, s2, s3);
    }
}

// ---------------- K5: atom GEMM + residual + in-register LN ----------------
template <bool AGGBF>
__global__ __launch_bounds__(256) void k_atom_mfma(
    const float* __restrict__ x, const float* __restrict__ aggf,
    const short* __restrict__ aggb,
    const short* __restrict__ Wp, const float* __restrict__ ba,
    const float* __restrict__ gn, const float* __restrict__ bn,
    float* __restrict__ out, int Nn)
{
    const int tid = threadIdx.x;
    const int ln = tid & 63, wv = tid >> 6;
    const int l15 = ln & 15, lhi = ln >> 4;
    const int nb = blockIdx.x * 128 + wv * 32;
    const s16x8* Bv = (const s16x8*)Wp;

    const float* xp[2];
    size_t nc[2];
    #pragma unroll
    for (int mt = 0; mt < 2; ++mt) {
        int n = nb + mt * 16 + l15;
        nc[mt] = (size_t)(n < Nn ? n : Nn - 1) * 128;
        xp[mt] = x + nc[mt];
    }

    f32x4 acc[2][8];
    #pragma unroll
    for (int m = 0; m < 2; ++m)
        #pragma unroll
        for (int n = 0; n < 8; ++n) acc[m][n] = (f32x4){0.f, 0.f, 0.f, 0.f};

    #pragma unroll 2
    for (int kt = 0; kt < 8; ++kt) {
        int ko = (kt & 3) * 32 + lhi * 8;
        s16x8 a[2];
        #pragma unroll
        for (int mt = 0; mt < 2; ++mt) {
            if (kt < 4) {
                const float* p = xp[mt] + ko;
                float buf[8];
                *(float4*)&buf[0] = *(const float4*)p;
                *(float4*)&buf[4] = *(const float4*)(p + 4);
                a[mt] = pack8(buf);
            } else if (AGGBF) {
                a[mt] = *(const s16x8*)(aggb + nc[mt] + ko);
            } else {
                const float* p = aggf + nc[mt] + ko;
                float buf[8];
                *(float4*)&buf[0] = *(const float4*)p;
                *(float4*)&buf[4] = *(const float4*)(p + 4);
                a[mt] = pack8(buf);
            }
        }
        const s16x8* brow = Bv + (size_t)(kt * 4 + lhi) * 128 + l15;
        #pragma unroll
        for (int nt = 0; nt < 8; ++nt) {
            s16x8 b = brow[nt * 16];
            acc[0][nt] = __builtin_amdgcn_mfma_f32_16x16x32_bf16(a[0], b, acc[0][nt], 0, 0, 0);
            acc[1][nt] = __builtin_amdgcn_mfma_f32_16x16x32_bf16(a[1], b, acc[1][nt], 0, 0, 0);
        }
    }

    #pragma unroll
    for (int mt = 0; mt < 2; ++mt)
        #pragma unroll
        for (int r = 0; r < 4; ++r) {
            int n = nb + mt * 16 + lhi * 4 + r;
            size_t nr = (size_t)(n < Nn ? n : 0) * 128;
            float s = 0.f, sq = 0.f;
            #pragma unroll
            for (int nt = 0; nt < 8; ++nt) {
                int col = nt * 16 + l15;
                float v = acc[mt][nt][r] + ba[col];
                float h = v / (1.f + __expf(-v));
                float t = x[nr + col] + h;
                acc[mt][nt][r] = t;
                s += t; sq += t * t;
            }
            #pragma unroll
            for (int o = 8; o; o >>= 1) {
                s  += __shfl_xor(s, o);
                sq += __shfl_xor(sq, o);
            }
            float mean = s * (1.f / 128.f);
            float var  = sq * (1.f / 128.f) - mean * mean;
            float rstd = rsqrtf(var + 1e-5f);
            if (n < Nn) {
                #pragma unroll
                for (int nt = 0; nt < 8; ++nt) {
                    int col = nt * 16 + l15;
                    float o = (acc[mt][nt][r] - mean) * rstd * gn[col] + bn[col];
                    out[(size_t)n * 128 + col] = o;
                }
            }
        }
}

// ---------------------------------------------------------------------------
extern "C" void kernel_launch(void* const* d_in, const int* in_sizes, int n_in,
                              void* d_out, int out_size, void* d_ws, size_t ws_size,
                              hipStream_t stream) {
    const float* x          = (const float*)d_in[0];
    const float* edge_attr  = (const float*)d_in[1];
    const float* lg_x       = (const float*)d_in[2];
    const float* lg_ea      = (const float*)d_in[3];
    const float* W_line     = (const float*)d_in[4];
    const float* b_line     = (const float*)d_in[5];
    const float* W_gate     = (const float*)d_in[6];
    const float* b_gate     = (const float*)d_in[7];
    const float* W_atom     = (const float*)d_in[8];
    const float* b_atom     = (const float*)d_in[9];
    const float* g_node     = (const float*)d_in[10];
    const float* beta_node  = (const float*)d_in[11];
    const float* g_edge     = (const float*)d_in[12];
    const float* beta_edge  = (const float*)d_in[13];
    const int*   edge_index    = (const int*)d_in[14];
    const int*   lg_edge_index = (const int*)d_in[15];

    const int Nn  = in_sizes[0] / 128;
    const int En  = in_sizes[1] / 128;
    const int LEn = in_sizes[3];

    float* out_x    = (float*)d_out;
    float* out_edge = out_x + (size_t)Nn * 128;
    float* out_lg   = out_edge + (size_t)En * 128;

    const int* lg_src = lg_edge_index;
    const int* lg_dst = lg_edge_index + LEn;
    const int* col    = edge_index + En;

    // ws layout
    short* wp_line = (short*)d_ws;            // 32768 shorts
    short* wp_gate = wp_line + 32768;         // 16384
    short* wp_atom = wp_gate + 16384;         // 32768
    int* ip = (int*)(wp_atom + 32768);
    int* off_lg  = ip;  ip += En + 1;
    int* deg_lg  = ip;  ip += En;             // deg+cur contiguous (1 memset)
    int* cur_lg  = ip;  ip += En;
    int* perm_lg = ip;  ip += LEn;
    int* bsum_lg = ip;  ip += 1024;
    int* off_at  = ip;  ip += Nn + 1;
    int* deg_at  = ip;  ip += Nn;
    int* cur_at  = ip;  ip += Nn;
    int* pos_at  = ip;  ip += En;
    int* bsum_at = ip;  ip += 1024;
    short* lgx_bf = (short*)(((uintptr_t)ip + 15) & ~(uintptr_t)15);
    short* bufA   = lgx_bf + (size_t)En * 128;       // msg, then gated (256 MB)
    short* agg_bf = bufA + (size_t)En * 128;         // 51 MB
    const size_t need_A = ((uintptr_t)(agg_bf + (size_t)Nn * 128)) - (uintptr_t)d_ws;
    const bool tierA = ws_size >= need_A;

    hipMemsetAsync(deg_lg, 0, (size_t)En * 8, stream);
    hipMemsetAsync(deg_at, 0, (size_t)Nn * 8, stream);

    const int nmax = LEn > En ? LEn : En;
    const int cvtBlocks = 2048;
    const int histBlocks = (nmax + 255) / 256;
    k_prep<<<40 + cvtBlocks + histBlocks, 256, 0, stream>>>(
        W_line, W_gate, W_atom, wp_line, wp_gate, wp_atom,
        lg_x, lgx_bf, (long)En * 16,
        lg_dst, deg_lg, LEn, col, deg_at, En, cvtBlocks);

    const int nb_lg = (En + SCAN_CHUNK - 1) / SCAN_CHUNK;
    const int nb_at = (Nn + SCAN_CHUNK - 1) / SCAN_CHUNK;
    k_scan_block2<<<nb_lg + nb_at, 256, 0, stream>>>(
        deg_lg, En, off_lg, bsum_lg, nb_lg, deg_at, Nn, off_at, bsum_at);
    k_scan_bsum2<<<1, 128, 0, stream>>>(bsum_lg, nb_lg, bsum_at, nb_at);
    const int sa_max = En > Nn ? En : Nn;
    k_scan_add2<<<(sa_max + 255) / 256, 256, 0, stream>>>(
        off_lg, bsum_lg, En, LEn, off_at, bsum_at, Nn, En);
    k_fill2<<<(nmax + 255) / 256, 256, 0, stream>>>(
        lg_dst, off_lg, cur_lg, perm_lg, LEn, col, off_at, cur_at, pos_at, En);

    if (tierA) {
        short* msg = bufA;
        k_line_csr<<<(LEn + 127) / 128, 256, 0, stream>>>(
            lgx_bf, lg_ea, wp_line, W_line, b_line, lg_src, lg_dst, perm_lg, msg, LEn);
        short* enew_bf = lgx_bf;             // same-thread same-index RAW only (r8-proven)
        k_lg_edge_fused<<<(En + 7) / 8, 256, 0, stream>>>(
            msg, lgx_bf, edge_attr, off_lg, g_edge, beta_edge,
            out_lg, out_edge, enew_bf, En);
        short* gated = bufA;                 // msg dead after fused gather
        k_gate_csr<true><<<(En + 127) / 128, 256, 0, stream>>>(
            enew_bf, nullptr, wp_gate, b_gate, pos_at, gated, En);
        k_atom_gather<true><<<(Nn + 7) / 8, 256, 0, stream>>>(
            gated, off_at, nullptr, agg_bf, Nn);
        k_atom_mfma<true><<<(Nn + 127) / 128, 256, 0, stream>>>(
            x, nullptr, agg_bf, wp_atom, b_atom, g_node, beta_node, out_x, Nn);
    } else {
        short* msgB = (short*)out_edge;      // scratch in d_out, overwritten later
        k_line_csr<<<(LEn + 127) / 128, 256, 0, stream>>>(
            lgx_bf, lg_ea, wp_line, W_line, b_line, lg_src, lg_dst, perm_lg, msgB, LEn);
        k_lg_gather<<<(En + 3) / 4, 256, 0, stream>>>(msgB, lg_x, off_lg, out_lg, En);
        k_edge_ln<<<(En + 3) / 4, 256, 0, stream>>>(
            out_lg, edge_attr, g_edge, beta_edge, out_edge, En);
        short* gatedB = lgx_bf;              // lgx_bf dead in tier B here
        k_gate_csr<false><<<(En + 127) / 128, 256, 0, stream>>>(
            nullptr, out_edge, wp_gate, b_gate, pos_at, gatedB, En);
        k_atom_gather<false><<<(Nn + 7) / 8, 256, 0, stream>>>(
            gatedB, off_at, out_x, nullptr, Nn);
        k_atom_mfma<false><<<(Nn + 127) / 128, 256, 0, stream>>>(
            x, out_x, nullptr, wp_atom, b_atom, g_node, beta_node, out_x, Nn);
    }
}